// Round 5
// baseline (50.871 us; speedup 1.0000x reference)
//
#include <hip/hip_runtime.h>

#define TPB   128
#define LSEQ  1024            // L
#define NCOL  1022            // n = L-2 (columns)
#define NROW  1021            // cumprod rows (= 127*8 + 5)
#define NPAD  1021            // leading zeros: index j-1-r+NPAD never < 0
#define SLDS  (NPAD + NCOL)   // 2043 floats = 8172 B LDS

// One thread owns ONE column j of one (batch, dir) matrix and walks the
// serial cumprod down all 1021 rows (uniform trip count, no divergence).
// p(r,j) = clamp01((v - s[j])*10 + 1), v = s[j-1-r] (0 if index < 0).
// LDS front-padded with zeros supplies the v=0 region without a select.
// Software pipeline: batch t+1's 8 ds_reads are issued BEFORE batch t's
// VALU+stores, so the ~120cy LDS latency hides under compute and the
// kernel runs into the HBM store-BW roofline.
__global__ __launch_bounds__(TPB) void gate_kernel(
    const float* __restrict__ score,
    const int*   __restrict__ score_idx,
    float*       __restrict__ out)
{
    __shared__ float sp[SLDS];

    const int bid = blockIdx.x;
    const int cb  = bid & 7;            // 8 column blocks x 128 threads
    const int bd  = bid >> 3;           // b*2 + d
    const int d   = bd & 1;
    const int b   = bd >> 1;
    const int tid = threadIdx.x;

    for (int i = tid; i < NPAD; i += TPB) sp[i] = 0.0f;
    const int* idxRow = score_idx + b * LSEQ + 1;      // docs[b][1:]
    for (int i = tid; i < NCOL; i += TPB) {
        int src = (d == 0) ? i : (NCOL - 1 - i);
        sp[NPAD + i] = score[idxRow[src]];
    }
    __syncthreads();

    const int j = cb * TPB + tid;
    if (j >= NCOL) return;              // 2 idle lanes in the last block

    const float c = 1.0f - 10.0f * sp[NPAD + j];
    float a = 1.0f;
    int   m = NPAD + j - 1;             // sp index of v at row r (descending)
    float* outp = out + (size_t)bd * NROW * NCOL + j;

#define ROW(X)                                                              \
    {   float p = fminf(fmaxf(__builtin_fmaf((X), 10.0f, c), 0.0f), 1.0f);  \
        a *= p; *outp = a; outp += NCOL; }

    // prologue: load batch 0
    float x0 = sp[m    ], x1 = sp[m - 1], x2 = sp[m - 2], x3 = sp[m - 3];
    float x4 = sp[m - 4], x5 = sp[m - 5], x6 = sp[m - 6], x7 = sp[m - 7];
    m -= 8;

    #pragma unroll 1
    for (int bt = 0; bt < NROW / 8 - 1; ++bt) {      // 126 iterations
        // issue next batch's reads first (independent of x*)
        float y0 = sp[m    ], y1 = sp[m - 1], y2 = sp[m - 2], y3 = sp[m - 3];
        float y4 = sp[m - 4], y5 = sp[m - 5], y6 = sp[m - 6], y7 = sp[m - 7];
        m -= 8;
        // consume current batch
        ROW(x0); ROW(x1); ROW(x2); ROW(x3);
        ROW(x4); ROW(x5); ROW(x6); ROW(x7);
        x0 = y0; x1 = y1; x2 = y2; x3 = y3;
        x4 = y4; x5 = y5; x6 = y6; x7 = y7;
    }

    // prefetch tail (5 rows), then consume last full batch
    float t0 = sp[m], t1 = sp[m - 1], t2 = sp[m - 2], t3 = sp[m - 3];
    float t4 = sp[m - 4];

    ROW(x0); ROW(x1); ROW(x2); ROW(x3);
    ROW(x4); ROW(x5); ROW(x6); ROW(x7);

    ROW(t0); ROW(t1); ROW(t2); ROW(t3); ROW(t4);
#undef ROW
}

extern "C" void kernel_launch(void* const* d_in, const int* in_sizes, int n_in,
                              void* d_out, int out_size, void* d_ws, size_t ws_size,
                              hipStream_t stream)
{
    const float* score = (const float*)d_in[0];
    const int*   sidx  = (const int*)d_in[1];
    float*       out   = (float*)d_out;

    const int B = in_sizes[0] / LSEQ;   // 32
    dim3 grid(B * 2 * 8), block(TPB);   // 512 blocks x 128 threads
    gate_kernel<<<grid, block, 0, stream>>>(score, sidx, out);
}